// Round 8
// baseline (377.516 us; speedup 1.0000x reference)
//
#include <hip/hip_runtime.h>
#include <hip/hip_fp16.h>

#define N_PTS 100000
#define KSZ 9
#define C_IN 24
#define C_HID 144
#define C_OUT 24
#define EPSV 1e-5f
#define NCH14 ((N_PTS + 13) / 14)                // 7143 chunks of 14 points
#define NPAIR (N_PTS / 2)                        // 50000

// ---- workspace layout (byte offsets) ----
// x1n: fp16 (N+1) x 144  RAW pre-BN y1  [0, 28,800,512)
// x2 : fp16  N    x 144  conv output    [28,800,512, 57,600,512)
// st : f32 stats                        [57,600,512, +4096)
// y3 : f32 N x 24  aliases x1n (x1n dead after conv)
#define X1N_B 0ull
#define X2_B  28800512ull
#define ST_B  57600512ull
#define Y3_B  0ull

// stat offsets (floats within ST)
#define MSUM1 0
#define MSQ1  160
#define MSUM2 320
#define MSQ2  480
#define MSUM3 640
#define MSQ3  672

typedef float f2v __attribute__((ext_vector_type(2)));
typedef float f4v __attribute__((ext_vector_type(4)));

__device__ inline float4 f4z() { return make_float4(0.f, 0.f, 0.f, 0.f); }
__device__ inline float4 f4_fma_s(float s, float4 b, float4 c) {
    return make_float4(fmaf(s, b.x, c.x), fmaf(s, b.y, c.y),
                       fmaf(s, b.z, c.z), fmaf(s, b.w, c.w));
}
__device__ inline float clamp6(float x) { return fminf(fmaxf(x, 0.f), 6.f); }

// ---- K1: GEMM1 (N,24)@(24,144) -> RAW y1 fp16, accumulate BN1 stats.
// 252 active threads: 7 point-pairs x 36 ch-groups (4 ch each).
// Sentinel row N = -inf halves: conv's clamp6(fma(-inf,sc,sh)) == 0
// (fmaxf(NaN,0)=0 covers sc==0), matching the reference zero row.
__global__ void __launch_bounds__(256)
k_gemm1(const float* __restrict__ feats, const float* __restrict__ w1,
        char* __restrict__ wsb) {
    __shared__ __align__(16) float smem[3744];   // w1 (3456) + lsum(144) + lsq(144)
    float* STF = (float*)(wsb + ST_B);
    __half* x1h = (__half*)(wsb + X1N_B);
    const int t = threadIdx.x;
    const int bid = blockIdx.x;
    for (int e = t; e < 864; e += 256) ((float4*)smem)[e] = ((const float4*)w1)[e];
    if (t < C_HID) { smem[3456 + t] = 0.f; smem[3600 + t] = 0.f; }
    if (bid == 0 && t < 72)
        ((unsigned int*)(x1h + (size_t)N_PTS * C_HID))[t] = 0xFC00FC00u;
    __syncthreads();
    const float4* w1s = (const float4*)smem;
    bool act = t < 252;
    int pt = t / 36, g = t % 36;
    float4 rs = f4z(), rq = f4z();
    for (int ch = bid; ch < NCH14; ch += (int)gridDim.x) {
        int pp = ch * 7 + pt;
        if (act && pp < NPAIR) {
            int p0 = pp * 2, p1 = p0 + 1;
            const float4* fa = (const float4*)(feats + (size_t)p0 * C_IN);
            const float4* fb = (const float4*)(feats + (size_t)p1 * C_IN);
            float4 A = f4z(), Bv = f4z();
#pragma unroll
            for (int q = 0; q < 6; q++) {
                float4 x = fa[q], y = fb[q];
                float4 w0 = w1s[(4 * q + 0) * 36 + g];
                float4 w1r = w1s[(4 * q + 1) * 36 + g];
                float4 w2r = w1s[(4 * q + 2) * 36 + g];
                float4 w3r = w1s[(4 * q + 3) * 36 + g];
                A = f4_fma_s(x.x, w0, A);  Bv = f4_fma_s(y.x, w0, Bv);
                A = f4_fma_s(x.y, w1r, A); Bv = f4_fma_s(y.y, w1r, Bv);
                A = f4_fma_s(x.z, w2r, A); Bv = f4_fma_s(y.z, w2r, Bv);
                A = f4_fma_s(x.w, w3r, A); Bv = f4_fma_s(y.w, w3r, Bv);
            }
            union { f2v f; __half2 h2[2]; } ua, ub;
            ua.h2[0] = __float22half2_rn(make_float2(A.x, A.y));
            ua.h2[1] = __float22half2_rn(make_float2(A.z, A.w));
            ub.h2[0] = __float22half2_rn(make_float2(Bv.x, Bv.y));
            ub.h2[1] = __float22half2_rn(make_float2(Bv.z, Bv.w));
            *(f2v*)(x1h + (size_t)p0 * C_HID + g * 4) = ua.f;
            *(f2v*)(x1h + (size_t)p1 * C_HID + g * 4) = ub.f;
            rs.x += A.x + Bv.x; rs.y += A.y + Bv.y;
            rs.z += A.z + Bv.z; rs.w += A.w + Bv.w;
            rq.x += A.x * A.x + Bv.x * Bv.x; rq.y += A.y * A.y + Bv.y * Bv.y;
            rq.z += A.z * A.z + Bv.z * Bv.z; rq.w += A.w * A.w + Bv.w * Bv.w;
        }
    }
    if (act) {
        atomicAdd(&smem[3456 + g * 4 + 0], rs.x);
        atomicAdd(&smem[3456 + g * 4 + 1], rs.y);
        atomicAdd(&smem[3456 + g * 4 + 2], rs.z);
        atomicAdd(&smem[3456 + g * 4 + 3], rs.w);
        atomicAdd(&smem[3600 + g * 4 + 0], rq.x);
        atomicAdd(&smem[3600 + g * 4 + 1], rq.y);
        atomicAdd(&smem[3600 + g * 4 + 2], rq.z);
        atomicAdd(&smem[3600 + g * 4 + 3], rq.w);
    }
    __syncthreads();
    if (t < C_HID) {
        atomicAdd(&STF[MSUM1 + t], smem[3456 + t]);
        atomicAdd(&STF[MSQ1 + t], smem[3600 + t]);
    }
}

// ---- K2: channelwise conv (round-1 proven body) + BN1 applied per-gather
//          + BN2 stat accumulation. 252 active: 14 points x 18 lanes (8 ch).
__global__ void k_conv(const float* __restrict__ w2, const float* __restrict__ g1,
                       const float* __restrict__ b1, const int* __restrict__ in_idx,
                       char* __restrict__ wsb) {
    __shared__ float w2s[KSZ * C_HID];
    __shared__ float lsum[C_HID], lsq[C_HID];
    float* STF = (float*)(wsb + ST_B);
    int t = threadIdx.x;
    for (int e = t; e < KSZ * C_HID; e += 256) w2s[e] = w2[e];
    if (t < C_HID) { lsum[t] = 0.f; lsq[t] = 0.f; }
    const bool act = t < 252;
    int pt = t / 18, g = t % 18, c0 = g * 8;
    float sc[8], sh[8];
    {
        const float invN = 1.f / (float)N_PTS;
#pragma unroll
        for (int j = 0; j < 8; j++) {
            int c = c0 + j;
            float mean = STF[MSUM1 + c] * invN;
            float var = STF[MSQ1 + c] * invN - mean * mean;
            float s = g1[c] * rsqrtf(var + EPSV);
            sc[j] = s;
            sh[j] = b1[c] - mean * s;
        }
    }
    __syncthreads();
    const __half* x1h = (const __half*)(wsb + X1N_B);
    __half* x2h = (__half*)(wsb + X2_B);
    float rs[8], rq[8];
#pragma unroll
    for (int j = 0; j < 8; j++) { rs[j] = 0.f; rq[j] = 0.f; }
    int ch = (int)blockIdx.x;
    int p = ch * 14 + pt;
    bool ok = act && p < N_PTS;
    int idxs[KSZ];
#pragma unroll
    for (int k = 0; k < KSZ; k++) idxs[k] = ok ? in_idx[k * N_PTS + p] : N_PTS;
    while (ch < NCH14) {
        float4 vv[KSZ];
#pragma unroll
        for (int k = 0; k < KSZ; k++)
            vv[k] = *(const float4*)(x1h + (size_t)idxs[k] * C_HID + c0);
        int chn = ch + (int)gridDim.x;
        int pn = chn * 14 + pt;
        bool okn = act && chn < NCH14 && pn < N_PTS;
        int idxn[KSZ];
#pragma unroll
        for (int k = 0; k < KSZ; k++) idxn[k] = okn ? in_idx[k * N_PTS + pn] : N_PTS;
        float acc[8];
#pragma unroll
        for (int j = 0; j < 8; j++) acc[j] = 0.f;
#pragma unroll
        for (int k = 0; k < KSZ; k++) {
            union { float4 f; __half2 h[4]; } u;
            u.f = vv[k];
#pragma unroll
            for (int jj = 0; jj < 4; jj++) {
                float2 x = __half22float2(u.h[jj]);
                float xa = clamp6(fmaf(x.x, sc[2 * jj], sh[2 * jj]));
                float xb = clamp6(fmaf(x.y, sc[2 * jj + 1], sh[2 * jj + 1]));
                acc[2 * jj]     = fmaf(w2s[k * C_HID + c0 + 2 * jj], xa, acc[2 * jj]);
                acc[2 * jj + 1] = fmaf(w2s[k * C_HID + c0 + 2 * jj + 1], xb, acc[2 * jj + 1]);
            }
        }
        if (ok) {
            union { f4v f; __half2 h[4]; } o;
#pragma unroll
            for (int jj = 0; jj < 4; jj++)
                o.h[jj] = __float22half2_rn(make_float2(acc[2 * jj], acc[2 * jj + 1]));
            __builtin_nontemporal_store(o.f, (f4v*)(x2h + (size_t)p * C_HID + c0));
        }
        // !ok lanes gathered the -inf sentinel -> xa,xb==0 -> acc==0 (harmless)
#pragma unroll
        for (int j = 0; j < 8; j++) {
            rs[j] += acc[j];
            rq[j] = fmaf(acc[j], acc[j], rq[j]);
        }
        ch = chn; p = pn; ok = okn;
#pragma unroll
        for (int k = 0; k < KSZ; k++) idxs[k] = idxn[k];
    }
    if (act) {
#pragma unroll
        for (int j = 0; j < 8; j++) {
            atomicAdd(&lsum[c0 + j], rs[j]);
            atomicAdd(&lsq[c0 + j], rq[j]);
        }
    }
    __syncthreads();
    if (t < C_HID) {
        atomicAdd(&STF[MSUM2 + t], lsum[t]);
        atomicAdd(&STF[MSQ2 + t], lsq[t]);
    }
}

// ---- K3: GEMM2 (N,144)@(144,24), BN2+relu6 on the fly, fused fin2 prologue
//          + fused BN3 stats (wave butterfly + block stage)
__global__ void k_gemm2(const float* __restrict__ w3, const float* __restrict__ g2,
                        const float* __restrict__ b2, char* __restrict__ wsb) {
    __shared__ float4 w3s[C_HID * 6];
    __shared__ float4 sc2v[C_HID / 4], sh2v[C_HID / 4];
    __shared__ float red[192];
    float* STF = (float*)(wsb + ST_B);
    int t = threadIdx.x;
    for (int e = t; e < C_HID * 6; e += 256) w3s[e] = ((const float4*)w3)[e];
    if (t < C_HID) {
        const float invN = 1.f / (float)N_PTS;
        float mean = STF[MSUM2 + t] * invN;
        float var = STF[MSQ2 + t] * invN - mean * mean;
        float s = g2[t] * rsqrtf(var + EPSV);
        ((float*)sc2v)[t] = s;
        ((float*)sh2v)[t] = b2[t] - mean * s;
    }
    __syncthreads();
    int r = blockIdx.x * 256 + t;
    bool ok = r < N_PTS;
    float4 a[6];
#pragma unroll
    for (int c4 = 0; c4 < 6; c4++) a[c4] = f4z();
    if (ok) {
        const float4* x2v = (const float4*)(wsb + X2_B + (size_t)r * (C_HID * 2));
#pragma unroll 3
        for (int h8 = 0; h8 < 18; h8++) {
            union { float4 f; __half2 h[4]; } u;
            u.f = x2v[h8];
            float4 s0 = sc2v[2 * h8], s1 = sc2v[2 * h8 + 1];
            float4 b0 = sh2v[2 * h8], b1v = sh2v[2 * h8 + 1];
            float2 x0 = __half22float2(u.h[0]);
            float2 x1 = __half22float2(u.h[1]);
            float2 x2 = __half22float2(u.h[2]);
            float2 x3 = __half22float2(u.h[3]);
            float xs[8];
            xs[0] = clamp6(fmaf(x0.x, s0.x, b0.x));
            xs[1] = clamp6(fmaf(x0.y, s0.y, b0.y));
            xs[2] = clamp6(fmaf(x1.x, s0.z, b0.z));
            xs[3] = clamp6(fmaf(x1.y, s0.w, b0.w));
            xs[4] = clamp6(fmaf(x2.x, s1.x, b1v.x));
            xs[5] = clamp6(fmaf(x2.y, s1.y, b1v.y));
            xs[6] = clamp6(fmaf(x3.x, s1.z, b1v.z));
            xs[7] = clamp6(fmaf(x3.y, s1.w, b1v.w));
#pragma unroll
            for (int j = 0; j < 8; j++) {
                int h = h8 * 8 + j;
#pragma unroll
                for (int c4 = 0; c4 < 6; c4++)
                    a[c4] = f4_fma_s(xs[j], w3s[h * 6 + c4], a[c4]);
            }
        }
        float4* y3v = (float4*)(wsb + Y3_B) + (size_t)r * 6;
#pragma unroll
        for (int c4 = 0; c4 < 6; c4++) y3v[c4] = a[c4];
    }
    int wv = t >> 6, ln = t & 63;
#pragma unroll
    for (int c4 = 0; c4 < 6; c4++) {
        float4 s = a[c4];
        float4 q = make_float4(s.x * s.x, s.y * s.y, s.z * s.z, s.w * s.w);
#pragma unroll
        for (int m = 1; m < 64; m <<= 1) {
            s.x += __shfl_xor(s.x, m); s.y += __shfl_xor(s.y, m);
            s.z += __shfl_xor(s.z, m); s.w += __shfl_xor(s.w, m);
            q.x += __shfl_xor(q.x, m); q.y += __shfl_xor(q.y, m);
            q.z += __shfl_xor(q.z, m); q.w += __shfl_xor(q.w, m);
        }
        if (ln == 0) {
            int base = wv * 48 + c4 * 4;
            red[base + 0] = s.x; red[base + 1] = s.y;
            red[base + 2] = s.z; red[base + 3] = s.w;
            red[base + 24 + 0] = q.x; red[base + 24 + 1] = q.y;
            red[base + 24 + 2] = q.z; red[base + 24 + 3] = q.w;
        }
    }
    __syncthreads();
    if (t < 48) {
        float v = red[t] + red[48 + t] + red[96 + t] + red[144 + t];
        if (t < 24) atomicAdd(&STF[MSUM3 + t], v);
        else        atomicAdd(&STF[MSQ3 + t - 24], v);
    }
}

// ---- K4: out = bn3(y3) + feats, fused fin3 prologue
__global__ void k_out(const float* __restrict__ feats, const float* __restrict__ g3,
                      const float* __restrict__ b3, const char* __restrict__ wsb,
                      float* __restrict__ out) {
    __shared__ float s3[C_OUT], h3[C_OUT];
    const float* STF = (const float*)(wsb + ST_B);
    int t = threadIdx.x;
    if (t < C_OUT) {
        const float invN = 1.f / (float)N_PTS;
        float mean = STF[MSUM3 + t] * invN;
        float var = STF[MSQ3 + t] * invN - mean * mean;
        float s = g3[t] * rsqrtf(var + EPSV);
        s3[t] = s;
        h3[t] = b3[t] - mean * s;
    }
    __syncthreads();
    int tau = blockIdx.x * 256 + t;
    if (tau >= N_PTS * 6) return;
    int c = (tau % 6) * 4;
    float4 y = ((const float4*)(wsb + Y3_B))[tau];
    float4 f = ((const float4*)feats)[tau];
    float4 o;
    o.x = fmaf(y.x, s3[c + 0], h3[c + 0]) + f.x;
    o.y = fmaf(y.y, s3[c + 1], h3[c + 1]) + f.y;
    o.z = fmaf(y.z, s3[c + 2], h3[c + 2]) + f.z;
    o.w = fmaf(y.w, s3[c + 3], h3[c + 3]) + f.w;
    ((float4*)out)[tau] = o;
}

extern "C" void kernel_launch(void* const* d_in, const int* in_sizes, int n_in,
                              void* d_out, int out_size, void* d_ws, size_t ws_size,
                              hipStream_t stream) {
    const float* feats = (const float*)d_in[0];
    const float* w1 = (const float*)d_in[1];
    const float* g1 = (const float*)d_in[2];
    const float* b1 = (const float*)d_in[3];
    const float* w2 = (const float*)d_in[4];
    const float* g2 = (const float*)d_in[5];
    const float* b2 = (const float*)d_in[6];
    const float* w3 = (const float*)d_in[7];
    const float* g3 = (const float*)d_in[8];
    const float* b3 = (const float*)d_in[9];
    const int* in_idx = (const int*)d_in[10];
    char* wsb = (char*)d_ws;
    float* out = (float*)d_out;

    (void)hipMemsetAsync(wsb + ST_B, 0, 4096, stream);
    hipLaunchKernelGGL(k_gemm1, dim3(2048), dim3(256), 0, stream, feats, w1, wsb);
    hipLaunchKernelGGL(k_conv, dim3(2048), dim3(256), 0, stream, w2, g1, b1, in_idx, wsb);
    hipLaunchKernelGGL(k_gemm2, dim3((N_PTS + 255) / 256), dim3(256), 0, stream,
                       w3, g2, b2, wsb);
    hipLaunchKernelGGL(k_out, dim3((N_PTS * 6 + 255) / 256), dim3(256), 0, stream,
                       feats, g3, b3, wsb, out);
}

// Round 9
// 309.209 us; speedup vs baseline: 1.2209x; 1.2209x over previous
//
#include <hip/hip_runtime.h>
#include <hip/hip_fp16.h>

#define N_PTS 100000
#define KSZ 9
#define C_IN 24
#define C_HID 144
#define C_OUT 24
#define EPSV 1e-5f
#define NCH14 ((N_PTS + 13) / 14)                // 7143 chunks of 14 points

// ---- workspace layout (byte offsets) ----
// x1n: fp16 (N+1) x 144  POST-ACT relu6(bn1(y1))  [0, 28,800,512)
// x2 : fp16  N    x 144  conv output              [28,800,512, 57,600,512)
// st : f32 stats                                  [57,600,512, +4096)
// y3 : f32 N x 24  aliases x1n (x1n dead after conv)
#define X1N_B 0ull
#define X2_B  28800512ull
#define ST_B  57600512ull
#define Y3_B  0ull

// stat offsets (floats within ST) — round-1 proven layout
#define MU1_F  0     // 24   raw sums of feats
#define M1_F   32    // 576  raw F^T F
#define SUM2_F 640   // 144
#define SQ2_F  800   // 144
#define SUM3_F 960   // 24
#define SQ3_F  992   // 24

typedef float f4v __attribute__((ext_vector_type(4)));

__device__ inline float4 f4z() { return make_float4(0.f, 0.f, 0.f, 0.f); }
__device__ inline float4 f4_fma_s(float s, float4 b, float4 c) {
    return make_float4(fmaf(s, b.x, c.x), fmaf(s, b.y, c.y),
                       fmaf(s, b.z, c.z), fmaf(s, b.w, c.w));
}
__device__ inline float clamp6(float x) { return fminf(fmaxf(x, 0.f), 6.f); }

// ---- K1: feats moments straight from global (round-1 verified, ~4 µs)
__global__ void k_moments(const float* __restrict__ feats, char* __restrict__ wsb) {
    int t = threadIdx.x;  // blockDim 640, 600 active
    float* STF = (float*)(wsb + ST_B);
    int len = (N_PTS + gridDim.x - 1) / gridDim.x;
    int r0 = blockIdx.x * len;
    int r1 = min(r0 + len, N_PTS);
    if (t >= 600) return;
    float a = 0.f;
    if (t < 576) {
        int i = t / 24, j = t % 24;
#pragma unroll 4
        for (int r = r0; r < r1; r++)
            a = fmaf(feats[(size_t)r * 24 + i], feats[(size_t)r * 24 + j], a);
        atomicAdd(&STF[M1_F + t], a);
    } else {
        int k = t - 576;
#pragma unroll 4
        for (int r = r0; r < r1; r++) a += feats[(size_t)r * 24 + k];
        atomicAdd(&STF[MU1_F + k], a);
    }
}

// ---- K2: GEMM1 (N,24)@(24,144) + BN1 + relu6 -> x1n fp16 (round-1 verified).
// Scalar 2B channel-mapped stores: this exact writer pattern leaves x1n in the
// L3-clean state that gives conv its 75 µs / 40 MB-FETCH behavior (rounds 1,4).
// DO NOT change to vector pair-mapped stores (round-8: conv FETCH 370 MB, 190 µs).
__global__ void __launch_bounds__(576, 5)
k_gemm1(const float* __restrict__ feats, const float* __restrict__ w1,
        const float* __restrict__ g1, const float* __restrict__ b1,
        char* __restrict__ wsb) {
    __shared__ float scs[C_HID], shs[C_HID];
    float* STF = (float*)(wsb + ST_B);
    int t = threadIdx.x;
    if (t < C_HID) {  // fin1 closed form from raw moments
        float wc[C_IN];
#pragma unroll
        for (int k = 0; k < C_IN; k++) wc[k] = w1[k * C_HID + t];
        const float invN = 1.f / (float)N_PTS;
        float mean = 0.f;
#pragma unroll
        for (int k = 0; k < C_IN; k++) mean = fmaf(STF[MU1_F + k], wc[k], mean);
        mean *= invN;
        float e2 = 0.f;
        for (int i = 0; i < C_IN; i++) {
            float s = 0.f;
#pragma unroll
            for (int j = 0; j < C_IN; j++) s = fmaf(STF[M1_F + i * 24 + j], wc[j], s);
            e2 = fmaf(wc[i], s, e2);
        }
        e2 *= invN;
        float var = e2 - mean * mean;
        float s1 = g1[t] * rsqrtf(var + EPSV);
        scs[t] = s1;
        shs[t] = b1[t] - mean * s1;
    }
    __syncthreads();
    int c = t % C_HID, pg = t / C_HID;  // pg in [0,4)
    float sc = scs[c];
    float sh = shs[c];
    float wreg[C_IN];
#pragma unroll
    for (int k = 0; k < C_IN; k++) wreg[k] = w1[k * C_HID + c] * sc;  // fold BN scale
    __half* x1h = (__half*)(wsb + X1N_B);
    for (int p = blockIdx.x * 4 + pg; p < N_PTS; p += gridDim.x * 4) {
        const float4* fr = (const float4*)(feats + (size_t)p * C_IN);
        float acc = sh;
#pragma unroll
        for (int q = 0; q < 6; q++) {
            float4 f = fr[q];
            acc = fmaf(f.x, wreg[4 * q + 0], acc);
            acc = fmaf(f.y, wreg[4 * q + 1], acc);
            acc = fmaf(f.z, wreg[4 * q + 2], acc);
            acc = fmaf(f.w, wreg[4 * q + 3], acc);
        }
        x1h[(size_t)p * C_HID + c] = __float2half_rn(clamp6(acc));
    }
}

// ---- K3: channelwise conv (round-1 verbatim, measured 74.6 µs):
// fp16 gather 16B/lane (18 lanes/row, 8ch), idx prefetch, NT x2 store,
// fused BN2 stat accumulation. Sentinel row N is zeros (memset).
__global__ void k_conv(const float* __restrict__ w2, const int* __restrict__ in_idx,
                       char* __restrict__ wsb) {
    __shared__ float w2s[KSZ * C_HID];
    __shared__ float lsum[C_HID], lsq[C_HID];
    float* STF = (float*)(wsb + ST_B);
    int t = threadIdx.x;
    for (int e = t; e < KSZ * C_HID; e += 256) w2s[e] = w2[e];
    if (t < C_HID) { lsum[t] = 0.f; lsq[t] = 0.f; }
    __syncthreads();
    const __half* x1h = (const __half*)(wsb + X1N_B);
    __half* x2h = (__half*)(wsb + X2_B);
    const bool act = t < 252;           // 14 points x 18 lanes
    int pt = t / 18, g = t % 18, c0 = g * 8;
    float rs[8], rq[8];
#pragma unroll
    for (int j = 0; j < 8; j++) { rs[j] = 0.f; rq[j] = 0.f; }
    int ch = (int)blockIdx.x;
    int p = ch * 14 + pt;
    bool ok = act && p < N_PTS;
    int idxs[KSZ];
#pragma unroll
    for (int k = 0; k < KSZ; k++) idxs[k] = ok ? in_idx[k * N_PTS + p] : N_PTS;
    while (ch < NCH14) {
        float4 vv[KSZ];
#pragma unroll
        for (int k = 0; k < KSZ; k++)
            vv[k] = *(const float4*)(x1h + (size_t)idxs[k] * C_HID + c0);
        int chn = ch + (int)gridDim.x;
        int pn = chn * 14 + pt;
        bool okn = act && chn < NCH14 && pn < N_PTS;
        int idxn[KSZ];
#pragma unroll
        for (int k = 0; k < KSZ; k++) idxn[k] = okn ? in_idx[k * N_PTS + pn] : N_PTS;
        float acc[8];
#pragma unroll
        for (int j = 0; j < 8; j++) acc[j] = 0.f;
#pragma unroll
        for (int k = 0; k < KSZ; k++) {
            union { float4 f; __half2 h[4]; } u;
            u.f = vv[k];
#pragma unroll
            for (int jj = 0; jj < 4; jj++) {
                float2 x = __half22float2(u.h[jj]);
                acc[2 * jj]     = fmaf(w2s[k * C_HID + c0 + 2 * jj], x.x, acc[2 * jj]);
                acc[2 * jj + 1] = fmaf(w2s[k * C_HID + c0 + 2 * jj + 1], x.y, acc[2 * jj + 1]);
            }
        }
        if (ok) {
            union { f4v f; __half2 h[4]; } o;
#pragma unroll
            for (int jj = 0; jj < 4; jj++)
                o.h[jj] = __float22half2_rn(make_float2(acc[2 * jj], acc[2 * jj + 1]));
            __builtin_nontemporal_store(o.f, (f4v*)(x2h + (size_t)p * C_HID + c0));
        }
        // !ok lanes gathered the zero sentinel -> acc==0 -> harmless for stats
#pragma unroll
        for (int j = 0; j < 8; j++) {
            rs[j] += acc[j];
            rq[j] = fmaf(acc[j], acc[j], rq[j]);
        }
        ch = chn; p = pn; ok = okn;
#pragma unroll
        for (int k = 0; k < KSZ; k++) idxs[k] = idxn[k];
    }
    if (act) {
#pragma unroll
        for (int j = 0; j < 8; j++) {
            atomicAdd(&lsum[c0 + j], rs[j]);
            atomicAdd(&lsq[c0 + j], rq[j]);
        }
    }
    __syncthreads();
    if (t < C_HID) {
        atomicAdd(&STF[SUM2_F + t], lsum[t]);
        atomicAdd(&STF[SQ2_F + t], lsq[t]);
    }
}

// ---- K4: GEMM2 (N,144)@(144,24), BN2+relu6 on the fly, fused fin2 prologue
//          + fused BN3 stats (wave butterfly + block stage) — round-4 verified
__global__ void k_gemm2(const float* __restrict__ w3, const float* __restrict__ g2,
                        const float* __restrict__ b2, char* __restrict__ wsb) {
    __shared__ float4 w3s[C_HID * 6];
    __shared__ float4 sc2v[C_HID / 4], sh2v[C_HID / 4];
    __shared__ float red[192];
    float* STF = (float*)(wsb + ST_B);
    int t = threadIdx.x;
    for (int e = t; e < C_HID * 6; e += 256) w3s[e] = ((const float4*)w3)[e];
    if (t < C_HID) {
        const float invN = 1.f / (float)N_PTS;
        float mean = STF[SUM2_F + t] * invN;
        float var = STF[SQ2_F + t] * invN - mean * mean;
        float s = g2[t] * rsqrtf(var + EPSV);
        ((float*)sc2v)[t] = s;
        ((float*)sh2v)[t] = b2[t] - mean * s;
    }
    __syncthreads();
    int r = blockIdx.x * 256 + t;
    bool ok = r < N_PTS;
    float4 a[6];
#pragma unroll
    for (int c4 = 0; c4 < 6; c4++) a[c4] = f4z();
    if (ok) {
        const float4* x2v = (const float4*)(wsb + X2_B + (size_t)r * (C_HID * 2));
#pragma unroll 3
        for (int h8 = 0; h8 < 18; h8++) {
            union { float4 f; __half2 h[4]; } u;
            u.f = x2v[h8];
            float4 s0 = sc2v[2 * h8], s1 = sc2v[2 * h8 + 1];
            float4 b0 = sh2v[2 * h8], b1v = sh2v[2 * h8 + 1];
            float2 x0 = __half22float2(u.h[0]);
            float2 x1 = __half22float2(u.h[1]);
            float2 x2 = __half22float2(u.h[2]);
            float2 x3 = __half22float2(u.h[3]);
            float xs[8];
            xs[0] = clamp6(fmaf(x0.x, s0.x, b0.x));
            xs[1] = clamp6(fmaf(x0.y, s0.y, b0.y));
            xs[2] = clamp6(fmaf(x1.x, s0.z, b0.z));
            xs[3] = clamp6(fmaf(x1.y, s0.w, b0.w));
            xs[4] = clamp6(fmaf(x2.x, s1.x, b1v.x));
            xs[5] = clamp6(fmaf(x2.y, s1.y, b1v.y));
            xs[6] = clamp6(fmaf(x3.x, s1.z, b1v.z));
            xs[7] = clamp6(fmaf(x3.y, s1.w, b1v.w));
#pragma unroll
            for (int j = 0; j < 8; j++) {
                int h = h8 * 8 + j;
#pragma unroll
                for (int c4 = 0; c4 < 6; c4++)
                    a[c4] = f4_fma_s(xs[j], w3s[h * 6 + c4], a[c4]);
            }
        }
        float4* y3v = (float4*)(wsb + Y3_B) + (size_t)r * 6;
#pragma unroll
        for (int c4 = 0; c4 < 6; c4++) y3v[c4] = a[c4];
    }
    int wv = t >> 6, ln = t & 63;
#pragma unroll
    for (int c4 = 0; c4 < 6; c4++) {
        float4 s = a[c4];
        float4 q = make_float4(s.x * s.x, s.y * s.y, s.z * s.z, s.w * s.w);
#pragma unroll
        for (int m = 1; m < 64; m <<= 1) {
            s.x += __shfl_xor(s.x, m); s.y += __shfl_xor(s.y, m);
            s.z += __shfl_xor(s.z, m); s.w += __shfl_xor(s.w, m);
            q.x += __shfl_xor(q.x, m); q.y += __shfl_xor(q.y, m);
            q.z += __shfl_xor(q.z, m); q.w += __shfl_xor(q.w, m);
        }
        if (ln == 0) {
            int base = wv * 48 + c4 * 4;
            red[base + 0] = s.x; red[base + 1] = s.y;
            red[base + 2] = s.z; red[base + 3] = s.w;
            red[base + 24 + 0] = q.x; red[base + 24 + 1] = q.y;
            red[base + 24 + 2] = q.z; red[base + 24 + 3] = q.w;
        }
    }
    __syncthreads();
    if (t < 48) {
        float v = red[t] + red[48 + t] + red[96 + t] + red[144 + t];
        if (t < 24) atomicAdd(&STF[SUM3_F + t], v);
        else        atomicAdd(&STF[SQ3_F + t - 24], v);
    }
}

// ---- K5: out = bn3(y3) + feats, fused fin3 prologue (round-4 verified)
__global__ void k_out(const float* __restrict__ feats, const float* __restrict__ g3,
                      const float* __restrict__ b3, const char* __restrict__ wsb,
                      float* __restrict__ out) {
    __shared__ float s3[C_OUT], h3[C_OUT];
    const float* STF = (const float*)(wsb + ST_B);
    int t = threadIdx.x;
    if (t < C_OUT) {
        const float invN = 1.f / (float)N_PTS;
        float mean = STF[SUM3_F + t] * invN;
        float var = STF[SQ3_F + t] * invN - mean * mean;
        float s = g3[t] * rsqrtf(var + EPSV);
        s3[t] = s;
        h3[t] = b3[t] - mean * s;
    }
    __syncthreads();
    int tau = blockIdx.x * 256 + t;
    if (tau >= N_PTS * 6) return;
    int c = (tau % 6) * 4;
    float4 y = ((const float4*)(wsb + Y3_B))[tau];
    float4 f = ((const float4*)feats)[tau];
    float4 o;
    o.x = fmaf(y.x, s3[c + 0], h3[c + 0]) + f.x;
    o.y = fmaf(y.y, s3[c + 1], h3[c + 1]) + f.y;
    o.z = fmaf(y.z, s3[c + 2], h3[c + 2]) + f.z;
    o.w = fmaf(y.w, s3[c + 3], h3[c + 3]) + f.w;
    ((float4*)out)[tau] = o;
}

extern "C" void kernel_launch(void* const* d_in, const int* in_sizes, int n_in,
                              void* d_out, int out_size, void* d_ws, size_t ws_size,
                              hipStream_t stream) {
    const float* feats = (const float*)d_in[0];
    const float* w1 = (const float*)d_in[1];
    const float* g1 = (const float*)d_in[2];
    const float* b1 = (const float*)d_in[3];
    const float* w2 = (const float*)d_in[4];
    const float* g2 = (const float*)d_in[5];
    const float* b2 = (const float*)d_in[6];
    const float* w3 = (const float*)d_in[7];
    const float* g3 = (const float*)d_in[8];
    const float* b3 = (const float*)d_in[9];
    const int* in_idx = (const int*)d_in[10];
    char* wsb = (char*)d_ws;
    float* out = (float*)d_out;

    // stats zero (4KB) + fp16 zero sentinel row N (288B)
    (void)hipMemsetAsync(wsb + ST_B, 0, 4096, stream);
    (void)hipMemsetAsync(wsb + (size_t)N_PTS * C_HID * 2, 0, C_HID * 2, stream);

    hipLaunchKernelGGL(k_moments, dim3(256), dim3(640), 0, stream, feats, wsb);
    hipLaunchKernelGGL(k_gemm1, dim3(1024), dim3(576), 0, stream, feats, w1, g1, b1, wsb);
    hipLaunchKernelGGL(k_conv, dim3(2048), dim3(256), 0, stream, w2, in_idx, wsb);
    hipLaunchKernelGGL(k_gemm2, dim3((N_PTS + 255) / 256), dim3(256), 0, stream,
                       w3, g2, b2, wsb);
    hipLaunchKernelGGL(k_out, dim3((N_PTS * 6 + 255) / 256), dim3(256), 0, stream,
                       feats, g3, b3, wsb, out);
}